// Round 9
// baseline (499.204 us; speedup 1.0000x reference)
//
#include <hip/hip_runtime.h>
#include <hip/hip_bf16.h>

#define N_NODES 50000
#define N_EDGES 800000
#define NFEAT 512
#define NHID 128
#define NCLASS 40
#define BN_EPS 1e-5f

typedef __attribute__((ext_vector_type(8))) short short8;
typedef __attribute__((ext_vector_type(4))) float f32x4;

#define GEMM1_BLOCKS ((N_NODES + 127) / 128)   // 391
#define EDGE_BLOCKS ((N_EDGES + 255) / 256)    // 3125
#define SCAN_BLOCKS ((N_NODES + 255) / 256)    // 196
#define BN_BLOCKS ((N_NODES + 255) / 256)      // 196
#define DEG8 (N_NODES * 8)                     // 400000 replicated counters

__device__ __forceinline__ unsigned short f2b(float f) {
    unsigned int u = __float_as_uint(f);
    u += 0x7fff + ((u >> 16) & 1);   // RTNE
    return (unsigned short)(u >> 16);
}
__device__ __forceinline__ float blo(unsigned int v) {
    return __uint_as_float(v << 16);
}
__device__ __forceinline__ float bhi(unsigned int v) {
    return __uint_as_float(v & 0xffff0000u);
}

// ---------------------------------------------------------------------------
// Fused: zero the 8-way replicated histogram + bf16 weight transpose prep.
__global__ void k_init_prep(unsigned long long* __restrict__ degcnt8,
                            const float* __restrict__ W1, const float* __restrict__ W2,
                            const float* __restrict__ W3, unsigned short* __restrict__ W1t,
                            unsigned short* __restrict__ W2t, unsigned short* __restrict__ W3t) {
    int i = blockIdx.x * blockDim.x + threadIdx.x;
    if (i < DEG8) { degcnt8[i] = 0ULL; return; }
    int j = i - DEG8;
    if (j < 65536) {
        int k = j >> 7, n = j & 127;
        W1t[n * 512 + k] = f2b(W1[j]);
    } else if (j < 81920) {
        int q = j - 65536; int k = q >> 7, n = q & 127;
        W2t[n * 128 + k] = f2b(W2[q]);
    } else if (j < 98304) {
        int q = j - 81920; int k = q >> 7, n = q & 127;
        W3t[n * 128 + k] = f2b(W3[q]);
    }
}

// ---------------------------------------------------------------------------
// FAT kernel: blocks [0,391) = layer-1 GEMM; blocks [391,391+3125) = edge
// convert + 8-way replicated degree histogram (copy = edge-block & 7, so the
// scatter can recompute it from e). One 64-bit atomic per edge: high word =
// per-copy count (returned old = within-copy CSR slot), low = 2^23 fixed-point
// ew sum (integer, exact across copies).
__global__ __launch_bounds__(256) void k_fat(
    const float* __restrict__ x, const unsigned short* __restrict__ W1t,
    unsigned short* __restrict__ hbuf,
    const unsigned int* __restrict__ words, const float* __restrict__ ew,
    int* __restrict__ row, int* __restrict__ col,
    unsigned long long* __restrict__ degcnt8, int* __restrict__ slot) {
    __shared__ unsigned short As[128][40];
    __shared__ unsigned short Bs[128][40];
    __shared__ int s_any;
    int tid = threadIdx.x;
    if (blockIdx.x < GEMM1_BLOCKS) {
        int m0 = blockIdx.x * 128;
        int srow = tid >> 1;
        int skh = (tid & 1) << 4;
        int wave = tid >> 6, lane = tid & 63;
        int wm = (wave >> 1) * 64, wn = (wave & 1) * 64;
        int l15 = lane & 15, quad = lane >> 4;
        f32x4 acc[4][4] = {};
        bool arow_ok = (m0 + srow) < N_NODES;
        const float* arow_p = x + (size_t)(m0 + srow) * 512 + skh;
        const unsigned short* wrow_p = W1t + (size_t)srow * 512 + skh;
        for (int kt = 0; kt < 512; kt += 32) {
            float v[16];
#pragma unroll
            for (int q = 0; q < 4; q++) {
                float4 t4 = make_float4(0.f, 0.f, 0.f, 0.f);
                if (arow_ok) t4 = *(const float4*)(arow_p + kt + q * 4);
                v[q * 4 + 0] = t4.x; v[q * 4 + 1] = t4.y;
                v[q * 4 + 2] = t4.z; v[q * 4 + 3] = t4.w;
            }
            unsigned int p[8];
#pragma unroll
            for (int q = 0; q < 8; q++)
                p[q] = (unsigned int)f2b(v[2 * q]) | ((unsigned int)f2b(v[2 * q + 1]) << 16);
            uint4 w0 = make_uint4(p[0], p[1], p[2], p[3]);
            uint4 w1 = make_uint4(p[4], p[5], p[6], p[7]);
            uint4 b0 = *(const uint4*)(wrow_p + kt);
            uint4 b1 = *(const uint4*)(wrow_p + kt + 8);
            *(uint4*)&As[srow][skh] = w0;
            *(uint4*)&As[srow][skh + 8] = w1;
            *(uint4*)&Bs[srow][skh] = b0;
            *(uint4*)&Bs[srow][skh + 8] = b1;
            __syncthreads();
            short8 a[4], b[4];
#pragma unroll
            for (int i = 0; i < 4; i++) a[i] = *(const short8*)&As[wm + i * 16 + l15][quad * 8];
#pragma unroll
            for (int j = 0; j < 4; j++) b[j] = *(const short8*)&Bs[wn + j * 16 + l15][quad * 8];
#pragma unroll
            for (int i = 0; i < 4; i++)
#pragma unroll
                for (int j = 0; j < 4; j++)
                    acc[i][j] = __builtin_amdgcn_mfma_f32_16x16x32_bf16(a[i], b[j], acc[i][j], 0, 0, 0);
            __syncthreads();
        }
#pragma unroll
        for (int i = 0; i < 4; i++) {
            int mb = m0 + wm + i * 16 + quad * 4;
#pragma unroll
            for (int r = 0; r < 4; r++) {
                int m = mb + r;
                if (m < N_NODES) {
#pragma unroll
                    for (int j = 0; j < 4; j++)
                        hbuf[(size_t)m * 128 + wn + j * 16 + l15] = f2b(acc[i][j][r]);
                }
            }
        }
    } else {
        if (tid == 0) s_any = 0;
        __syncthreads();
        unsigned int probe = words[2 * tid + 1];
        if (probe != 0) atomicAdd(&s_any, 1);
        __syncthreads();
        int f = (s_any == 0) ? 1 : 0;  // 1 => int64 layout
        int eb = blockIdx.x - GEMM1_BLOCKS;
        int e = eb * 256 + tid;
        int copy = eb & 7;
        if (e < N_EDGES) {
            unsigned int r = f ? words[2 * (size_t)e] : words[e];
            unsigned int c = f ? words[2 * ((size_t)e + N_EDGES)] : words[e + N_EDGES];
            row[e] = (int)r;
            col[e] = (int)c;
            unsigned int q = __float2uint_rn(ew[e] * 8388608.0f);  // 2^23 fixed point
            unsigned long long old = atomicAdd(&degcnt8[(size_t)c * 8 + copy],
                                               (1ULL << 32) | (unsigned long long)q);
            slot[e] = (int)(old >> 32);
        }
    }
}

// ---------------------------------------------------------------------------
// dinv + per-copy slot bases + total counts + scan phase-1 block reduction.
__global__ __launch_bounds__(256) void k_dinv(const unsigned long long* __restrict__ degcnt8,
                                              float* __restrict__ dinv,
                                              int* __restrict__ counts,
                                              int* __restrict__ base8,
                                              int* __restrict__ bsum) {
    int i = blockIdx.x * 256 + threadIdx.x;
    int cnt = 0;
    if (i < N_NODES) {
        unsigned int fx = 0;
        int run = 0;
#pragma unroll
        for (int c = 0; c < 8; c++) {
            unsigned long long v = degcnt8[(size_t)i * 8 + c];
            base8[i * 8 + c] = run;
            run += (int)(v >> 32);
            fx += (unsigned int)(v & 0xffffffffULL);
        }
        float deg = 1.0f + (float)fx * (1.0f / 8388608.0f);
        dinv[i] = rsqrtf(deg);
        counts[i] = run;
        cnt = run;
    }
    __shared__ int sh[256];
    sh[threadIdx.x] = cnt;
    __syncthreads();
    for (int ofs = 128; ofs > 0; ofs >>= 1) {
        if (threadIdx.x < ofs) sh[threadIdx.x] += sh[threadIdx.x + ofs];
        __syncthreads();
    }
    if (threadIdx.x == 0) bsum[blockIdx.x] = sh[0];
}

// ---------------------------------------------------------------------------
// Scan: each block redundantly scans the 196 block sums in LDS (merges the old
// scan2 launch), then block-local exclusive scan of counts -> colptr.
__global__ __launch_bounds__(256) void k_scan(const int* __restrict__ counts,
                                              const int* __restrict__ bsum,
                                              int* __restrict__ colptr) {
    int t = threadIdx.x;
    __shared__ int shb[256];
    int vb = (t < SCAN_BLOCKS) ? bsum[t] : 0;
    shb[t] = vb;
    __syncthreads();
    for (int ofs = 1; ofs < 256; ofs <<= 1) {
        int u = (t >= ofs) ? shb[t - ofs] : 0;
        __syncthreads();
        shb[t] += u;
        __syncthreads();
    }
    int bpre = (blockIdx.x > 0) ? shb[blockIdx.x - 1] : 0;
    int total = shb[SCAN_BLOCKS - 1];
    __shared__ int sh[256];
    int i = blockIdx.x * 256 + t;
    int v = (i < N_NODES) ? counts[i] : 0;
    sh[t] = v;
    __syncthreads();
    for (int ofs = 1; ofs < 256; ofs <<= 1) {
        int u = (t >= ofs) ? sh[t - ofs] : 0;
        __syncthreads();
        sh[t] += u;
        __syncthreads();
    }
    if (i < N_NODES) colptr[i] = bpre + sh[t] - v;
    if (blockIdx.x == 0 && t == 0) colptr[N_NODES] = total;
}

// Atomic-free scatter: p = colptr[c] + per-copy base + within-copy slot.
__global__ void k_scatter(const int* __restrict__ row, const int* __restrict__ col,
                          const float* __restrict__ ew, const float* __restrict__ dinv,
                          const int* __restrict__ colptr, const int* __restrict__ base8,
                          const int* __restrict__ slot, int2* __restrict__ ern) {
    int e = blockIdx.x * blockDim.x + threadIdx.x;
    if (e < N_EDGES) {
        int c = col[e], r = row[e];
        int copy = (e >> 8) & 7;
        int p = colptr[c] + base8[c * 8 + copy] + slot[e];
        float nrm = dinv[r] * ew[e] * dinv[c];
        ern[p] = make_int2(r, __float_as_int(nrm));
    }
}

// ---------------------------------------------------------------------------
// CSR aggregation: one wave per node, h bf16, fp32 accumulate, 8-way unrolled.
// Block 0 zeroes sums/sumsq for the following bnstats (stream order safe).
__global__ __launch_bounds__(256) void k_aggregate(
    const unsigned int* __restrict__ hb, const int* __restrict__ colptr,
    const int2* __restrict__ ern, const float* __restrict__ dinv,
    const float* __restrict__ bias, unsigned int* __restrict__ out, int relu,
    float* __restrict__ sums, float* __restrict__ sumsq) {
    if (blockIdx.x == 0) {
        if (threadIdx.x < 128) sums[threadIdx.x] = 0.f;
        else sumsq[threadIdx.x - 128] = 0.f;
    }
    int node = (blockIdx.x * blockDim.x + threadIdx.x) >> 6;
    int lane = threadIdx.x & 63;
    if (node >= N_NODES) return;
    float di = dinv[node];
    float selfw = di * di;
    unsigned int sv = hb[(size_t)node * 64 + lane];
    float a0 = selfw * blo(sv);
    float a1 = selfw * bhi(sv);
    float c0 = 0.f, c1 = 0.f;
    int e = colptr[node], end = colptr[node + 1];
    for (; e + 8 <= end; e += 8) {
        int2 rw[8];
#pragma unroll
        for (int q = 0; q < 8; q++) rw[q] = ern[e + q];
        unsigned int v[8];
#pragma unroll
        for (int q = 0; q < 8; q++) v[q] = hb[(size_t)rw[q].x * 64 + lane];
#pragma unroll
        for (int q = 0; q < 8; q++) {
            float w = __int_as_float(rw[q].y);
            if (q & 1) { c0 += w * blo(v[q]); c1 += w * bhi(v[q]); }
            else       { a0 += w * blo(v[q]); a1 += w * bhi(v[q]); }
        }
    }
    for (; e < end; e++) {
        int2 rw = ern[e];
        float w = __int_as_float(rw.y);
        unsigned int v = hb[(size_t)rw.x * 64 + lane];
        a0 += w * blo(v);
        a1 += w * bhi(v);
    }
    a0 += c0; a1 += c1;
    float2 bv = *(const float2*)&bias[2 * lane];
    a0 += bv.x;
    a1 += bv.y;
    if (relu) { a0 = fmaxf(a0, 0.f); a1 = fmaxf(a1, 0.f); }
    out[(size_t)node * 64 + lane] = (unsigned int)f2b(a0) | ((unsigned int)f2b(a1) << 16);
}

// ---------------------------------------------------------------------------
// BatchNorm stats: per-block partials, atomically folded into sums/sumsq[128].
__global__ __launch_bounds__(256) void k_bnstats(const unsigned int* __restrict__ x,
                                                 float* __restrict__ sums,
                                                 float* __restrict__ sumsq) {
    int u = threadIdx.x & 63;
    int strip = threadIdx.x >> 6;
    int r0 = blockIdx.x * 256;
    int rend = min(r0 + 256, N_NODES);
    float sl = 0.f, s2l = 0.f, sh_ = 0.f, s2h = 0.f;
    for (int r = r0 + strip; r < rend; r += 4) {
        unsigned int v = x[(size_t)r * 64 + u];
        float a = blo(v), b = bhi(v);
        sl += a; s2l += a * a;
        sh_ += b; s2h += b * b;
    }
    __shared__ float buf[4][64][4];
    buf[strip][u][0] = sl; buf[strip][u][1] = s2l;
    buf[strip][u][2] = sh_; buf[strip][u][3] = s2h;
    __syncthreads();
    if (strip == 0) {
#pragma unroll
        for (int s = 1; s < 4; s++) {
            sl += buf[s][u][0]; s2l += buf[s][u][1];
            sh_ += buf[s][u][2]; s2h += buf[s][u][3];
        }
        atomicAdd(&sums[2 * u], sl);
        atomicAdd(&sums[2 * u + 1], sh_);
        atomicAdd(&sumsq[2 * u], s2l);
        atomicAdd(&sumsq[2 * u + 1], s2h);
    }
}

// ---------------------------------------------------------------------------
// Layer-2/3 GEMM: A bf16-packed, BN scale/shift computed inline in prologue.
__global__ __launch_bounds__(256) void k_gemm_h(
    const unsigned int* __restrict__ Ab, const unsigned short* __restrict__ Wt,
    const float* __restrict__ sums, const float* __restrict__ sumsq,
    const float* __restrict__ g, const float* __restrict__ be,
    unsigned short* __restrict__ Out) {
    __shared__ unsigned short As[128][40];
    __shared__ unsigned short Bs[128][40];
    __shared__ float s_sc[128], s_sh[128];
    int tid = threadIdx.x;
    int m0 = blockIdx.x * 128;
    if (tid < 128) {
        const float invn = 1.0f / (float)N_NODES;
        float mu = sums[tid] * invn;
        float var = sumsq[tid] * invn - mu * mu;
        float iv = rsqrtf(var + BN_EPS);
        float sc = g[tid] * iv;
        s_sc[tid] = sc;
        s_sh[tid] = be[tid] - mu * sc;
    }
    __syncthreads();
    int srow = tid >> 1;
    int skh = (tid & 1) << 4;
    int wave = tid >> 6, lane = tid & 63;
    int wm = (wave >> 1) * 64, wn = (wave & 1) * 64;
    int l15 = lane & 15, quad = lane >> 4;
    f32x4 acc[4][4] = {};
    bool arow_ok = (m0 + srow) < N_NODES;
    const unsigned int* arow_b = Ab + (size_t)(m0 + srow) * 64 + (skh >> 1);
    const unsigned short* wrow_p = Wt + (size_t)srow * 128 + skh;
    for (int kt = 0; kt < 128; kt += 32) {
        uint4 r0 = make_uint4(0, 0, 0, 0), r1 = make_uint4(0, 0, 0, 0);
        if (arow_ok) {
            r0 = *(const uint4*)(arow_b + (kt >> 1));
            r1 = *(const uint4*)(arow_b + (kt >> 1) + 4);
        }
        unsigned int raw[8] = {r0.x, r0.y, r0.z, r0.w, r1.x, r1.y, r1.z, r1.w};
        unsigned int p[8];
#pragma unroll
        for (int q = 0; q < 8; q++) {
            int ch = kt + skh + 2 * q;
            float f0 = blo(raw[q]) * s_sc[ch] + s_sh[ch];
            float f1 = bhi(raw[q]) * s_sc[ch + 1] + s_sh[ch + 1];
            p[q] = (unsigned int)f2b(f0) | ((unsigned int)f2b(f1) << 16);
        }
        uint4 w0 = make_uint4(p[0], p[1], p[2], p[3]);
        uint4 w1 = make_uint4(p[4], p[5], p[6], p[7]);
        uint4 b0 = *(const uint4*)(wrow_p + kt);
        uint4 b1 = *(const uint4*)(wrow_p + kt + 8);
        *(uint4*)&As[srow][skh] = w0;
        *(uint4*)&As[srow][skh + 8] = w1;
        *(uint4*)&Bs[srow][skh] = b0;
        *(uint4*)&Bs[srow][skh + 8] = b1;
        __syncthreads();
        short8 a[4], b[4];
#pragma unroll
        for (int i = 0; i < 4; i++) a[i] = *(const short8*)&As[wm + i * 16 + l15][quad * 8];
#pragma unroll
        for (int j = 0; j < 4; j++) b[j] = *(const short8*)&Bs[wn + j * 16 + l15][quad * 8];
#pragma unroll
        for (int i = 0; i < 4; i++)
#pragma unroll
            for (int j = 0; j < 4; j++)
                acc[i][j] = __builtin_amdgcn_mfma_f32_16x16x32_bf16(a[i], b[j], acc[i][j], 0, 0, 0);
        __syncthreads();
    }
#pragma unroll
    for (int i = 0; i < 4; i++) {
        int mb = m0 + wm + i * 16 + quad * 4;
#pragma unroll
        for (int r = 0; r < 4; r++) {
            int m = mb + r;
            if (m < N_NODES) {
#pragma unroll
                for (int j = 0; j < 4; j++)
                    Out[(size_t)m * 128 + wn + j * 16 + l15] = f2b(acc[i][j][r]);
            }
        }
    }
}

// ---------------------------------------------------------------------------
// Head: BN3 scale/shift inline, x3 fp32 write, logits+softmax.
__global__ __launch_bounds__(256) void k_logits(const unsigned int* __restrict__ abuf,
                                                const float* __restrict__ sums,
                                                const float* __restrict__ sumsq,
                                                const float* __restrict__ g,
                                                const float* __restrict__ be,
                                                const float* __restrict__ linW,
                                                const float* __restrict__ linb,
                                                float* __restrict__ logits,
                                                float* __restrict__ probs,
                                                float* __restrict__ x3out) {
    __shared__ float Xs[64][130];
    __shared__ float Ws[128 * 40];
    __shared__ float s_sc[128], s_sh[128];
    int tid = threadIdx.x;
    int m0 = blockIdx.x * 64;
    if (tid < 128) {
        const float invn = 1.0f / (float)N_NODES;
        float mu = sums[tid] * invn;
        float var = sumsq[tid] * invn - mu * mu;
        float iv = rsqrtf(var + BN_EPS);
        float sc = g[tid] * iv;
        s_sc[tid] = sc;
        s_sh[tid] = be[tid] - mu * sc;
    }
    for (int q = tid; q < 1280; q += 256)
        *(float4*)&Ws[q * 4] = *(const float4*)&linW[q * 4];
    __syncthreads();
    for (int q = tid; q < 4096; q += 256) {
        int r = q >> 6, u = q & 63;
        int m = m0 + r;
        float f0 = 0.f, f1 = 0.f;
        if (m < N_NODES) {
            unsigned int v = abuf[(size_t)m * 64 + u];
            f0 = blo(v) * s_sc[2 * u] + s_sh[2 * u];
            f1 = bhi(v) * s_sc[2 * u + 1] + s_sh[2 * u + 1];
            *(float2*)&x3out[(size_t)m * 128 + 2 * u] = make_float2(f0, f1);
        }
        *(float2*)&Xs[r][2 * u] = make_float2(f0, f1);
    }
    __syncthreads();
    int r = tid >> 2;
    int cg = tid & 3;
    int cbase = cg * 10;
    float acc[10] = {};
    for (int k = 0; k < 128; k++) {
        float a = Xs[r][k];
#pragma unroll
        for (int j = 0; j < 10; j++) acc[j] += a * Ws[k * 40 + cbase + j];
    }
#pragma unroll
    for (int j = 0; j < 10; j++) acc[j] += linb[cbase + j];
    float m = acc[0];
#pragma unroll
    for (int j = 1; j < 10; j++) m = fmaxf(m, acc[j]);
    m = fmaxf(m, __shfl_xor(m, 1));
    m = fmaxf(m, __shfl_xor(m, 2));
    float ex[10];
    float s = 0.f;
#pragma unroll
    for (int j = 0; j < 10; j++) { ex[j] = expf(acc[j] - m); s += ex[j]; }
    s += __shfl_xor(s, 1);
    s += __shfl_xor(s, 2);
    float inv = 1.0f / s;
    int mrow = m0 + r;
    if (mrow < N_NODES) {
#pragma unroll
        for (int j = 0; j < 10; j++) {
            logits[(size_t)mrow * 40 + cbase + j] = acc[j];
            probs[(size_t)mrow * 40 + cbase + j] = ex[j] * inv;
        }
    }
}

// ---------------------------------------------------------------------------
extern "C" void kernel_launch(void* const* d_in, const int* in_sizes, int n_in,
                              void* d_out, int out_size, void* d_ws, size_t ws_size,
                              hipStream_t stream) {
    const float* x = (const float*)d_in[0];
    const unsigned int* eidx = (const unsigned int*)d_in[1];
    const float* ew = (const float*)d_in[2];
    const float* W1 = (const float*)d_in[3];
    const float* b1 = (const float*)d_in[4];
    const float* W2 = (const float*)d_in[5];
    const float* b2 = (const float*)d_in[6];
    const float* W3 = (const float*)d_in[7];
    const float* b3 = (const float*)d_in[8];
    const float* g1 = (const float*)d_in[9];
    const float* be1 = (const float*)d_in[10];
    const float* g2 = (const float*)d_in[11];
    const float* be2 = (const float*)d_in[12];
    const float* g3 = (const float*)d_in[13];
    const float* be3 = (const float*)d_in[14];
    const float* linW = (const float*)d_in[15];
    const float* linb = (const float*)d_in[16];

    float* out = (float*)d_out;
    float* logits = out;
    float* probs = out + (size_t)N_NODES * NCLASS;
    float* x3out = out + 2 * (size_t)N_NODES * NCLASS;

    char* ws = (char*)d_ws;
    size_t off = 0;
    auto take = [&](size_t bytes) -> char* {
        char* p = ws + off;
        off += (bytes + 255) & ~(size_t)255;
        return p;
    };
    int* row32 = (int*)take((size_t)N_EDGES * 4);
    int* col32 = (int*)take((size_t)N_EDGES * 4);
    int* slot = (int*)take((size_t)N_EDGES * 4);
    int* colptr = (int*)take((size_t)(N_NODES + 1) * 4);
    int* counts = (int*)take((size_t)N_NODES * 4);
    unsigned long long* degcnt8 = (unsigned long long*)take((size_t)DEG8 * 8);
    int* base8 = (int*)take((size_t)DEG8 * 4);
    int2* ern = (int2*)take((size_t)N_EDGES * 8);
    float* dinv = (float*)take((size_t)N_NODES * 4);
    unsigned short* hbuf = (unsigned short*)take((size_t)N_NODES * NHID * 2);
    unsigned short* abuf = (unsigned short*)take((size_t)N_NODES * NHID * 2);
    unsigned short* W1t = (unsigned short*)take((size_t)512 * 128 * 2);
    unsigned short* W2t = (unsigned short*)take((size_t)128 * 128 * 2);
    unsigned short* W3t = (unsigned short*)take((size_t)128 * 128 * 2);
    float* sums = (float*)take(128 * 4);
    float* sumsq = (float*)take(128 * 4);
    int* bsum = (int*)take((size_t)SCAN_BLOCKS * 4);
    (void)ws_size; (void)n_in; (void)in_sizes; (void)out_size;

    const int TPB = 256;
    int grid_initprep = (DEG8 + 98304 + TPB - 1) / TPB;
    int grid_gemm = GEMM1_BLOCKS;                 // 391
    int grid_agg = (N_NODES * 64 + TPB - 1) / TPB;
    int grid_head = (N_NODES + 63) / 64;          // 782

    // preprocessing
    k_init_prep<<<grid_initprep, TPB, 0, stream>>>(degcnt8, W1, W2, W3, W1t, W2t, W3t);
    k_fat<<<GEMM1_BLOCKS + EDGE_BLOCKS, TPB, 0, stream>>>(
        x, W1t, hbuf, eidx, ew, row32, col32, degcnt8, slot);
    k_dinv<<<SCAN_BLOCKS, TPB, 0, stream>>>(degcnt8, dinv, counts, base8, bsum);
    k_scan<<<SCAN_BLOCKS, TPB, 0, stream>>>(counts, bsum, colptr);
    k_scatter<<<EDGE_BLOCKS, TPB, 0, stream>>>(row32, col32, ew, dinv, colptr, base8, slot, ern);

    // layer 1
    k_aggregate<<<grid_agg, TPB, 0, stream>>>((const unsigned int*)hbuf, colptr, ern, dinv, b1, (unsigned int*)abuf, 1, sums, sumsq);
    k_bnstats<<<BN_BLOCKS, TPB, 0, stream>>>((const unsigned int*)abuf, sums, sumsq);

    // layer 2
    k_gemm_h<<<grid_gemm, TPB, 0, stream>>>((const unsigned int*)abuf, W2t, sums, sumsq, g1, be1, hbuf);
    k_aggregate<<<grid_agg, TPB, 0, stream>>>((const unsigned int*)hbuf, colptr, ern, dinv, b2, (unsigned int*)abuf, 1, sums, sumsq);
    k_bnstats<<<BN_BLOCKS, TPB, 0, stream>>>((const unsigned int*)abuf, sums, sumsq);

    // layer 3
    k_gemm_h<<<grid_gemm, TPB, 0, stream>>>((const unsigned int*)abuf, W3t, sums, sumsq, g2, be2, hbuf);
    k_aggregate<<<grid_agg, TPB, 0, stream>>>((const unsigned int*)hbuf, colptr, ern, dinv, b3, (unsigned int*)abuf, 0, sums, sumsq);
    k_bnstats<<<BN_BLOCKS, TPB, 0, stream>>>((const unsigned int*)abuf, sums, sumsq);

    // head
    k_logits<<<grid_head, TPB, 0, stream>>>((const unsigned int*)abuf, sums, sumsq, g3, be3, linW, linb, logits, probs, x3out);
}